// Round 5
// baseline (844.514 us; speedup 1.0000x reference)
//
#include <hip/hip_runtime.h>
#include <hip/hip_bf16.h>
#include <stdint.h>

#define B_ 4
#define S_ 2048
#define D_ 1024
#define H_ 4
#define DH_ 256
#define BHS_ (B_ * H_ * S_)

typedef __bf16 bf16x8 __attribute__((ext_vector_type(8)));
typedef float f32x4 __attribute__((ext_vector_type(4)));

#define MFMA16(a, b, c) __builtin_amdgcn_mfma_f32_16x16x32_bf16(a, b, c, 0, 0, 0)

typedef __attribute__((address_space(1))) const unsigned int gu32;
typedef __attribute__((address_space(3))) unsigned int lu32;
#define GLD16(g, l) __builtin_amdgcn_global_load_lds((gu32*)(g), (lu32*)(l), 16, 0, 0)

__device__ __forceinline__ short f2bf(float f) {
    __bf16 h = (__bf16)f;
    return __builtin_bit_cast(short, h);
}

// ---------------- fp32 -> bf16 convert (vectorized) ----------------
__global__ void cvt_kernel(const float* __restrict__ src, short* __restrict__ dst, int n4) {
    int i = blockIdx.x * blockDim.x + threadIdx.x;
    if (i >= n4) return;
    float4 f = ((const float4*)src)[i];
    short4 o;
    o.x = f2bf(f.x); o.y = f2bf(f.y); o.z = f2bf(f.z); o.w = f2bf(f.w);
    ((short4*)dst)[i] = o;
}

// ---------------- generic B^T GEMM: C = A * B^T (+bias, per-mode epilogue) ---
// MODE 0: qs  = (A*W^T + qb)/16 -> bf16 [B,H,S,DH]   (1/sqrt(DH) folded in)
// MODE 1: ks  = (A*W^T + kb)    -> bf16 [B,H,S,DH]
// MODE 2: vsT = (vW*v^T + vb[row]) -> bf16 [B,DH,S]
// MODE 3: out = A*W^T (f32) -> d_out [B,S,D]
template<int MODE>
__global__ __launch_bounds__(256)
void gemm_bt(const short* __restrict__ A, long sA, int lda,
             const short* __restrict__ Bw, long sB, int ldb,
             const float* __restrict__ bias,
             void* __restrict__ outp, int K) {
    __shared__ short Ash[128 * 64];
    __shared__ short Bsh[128 * 64];
    const int tid = threadIdx.x, wid = tid >> 6, lane = tid & 63;
    const int bz = blockIdx.z;
    const int tile_m = blockIdx.y * 128, tile_n = blockIdx.x * 128;
    const short* Ab = A + (long)bz * sA + (long)tile_m * lda;
    const short* Bb = Bw + (long)bz * sB + (long)tile_n * ldb;
    const int wr = wid >> 1, wc = wid & 1;

    f32x4 acc[4][4];
#pragma unroll
    for (int i = 0; i < 4; i++)
#pragma unroll
        for (int j = 0; j < 4; j++) acc[i][j] = {0.f, 0.f, 0.f, 0.f};

    for (int k0 = 0; k0 < K; k0 += 64) {
        __syncthreads();
#pragma unroll
        for (int i = 0; i < 4; i++) {
            int off = ((i * 4 + wid) * 64 + lane) * 16;  // byte offset in 16KB tile
            int row = off >> 7;
            int col = (off & 127) >> 1;  // element col
            GLD16(Ab + row * lda + k0 + col, ((char*)Ash) + off);
            GLD16(Bb + row * ldb + k0 + col, ((char*)Bsh) + off);
        }
        __syncthreads();
#pragma unroll
        for (int kk = 0; kk < 2; kk++) {
            bf16x8 af[4];
#pragma unroll
            for (int mi = 0; mi < 4; mi++)
                af[mi] = *(const bf16x8*)&Ash[(wr * 64 + mi * 16 + (lane & 15)) * 64 + kk * 32 + (lane >> 4) * 8];
#pragma unroll
            for (int ni = 0; ni < 4; ni++) {
                bf16x8 bfr = *(const bf16x8*)&Bsh[(wc * 64 + ni * 16 + (lane & 15)) * 64 + kk * 32 + (lane >> 4) * 8];
#pragma unroll
                for (int mi = 0; mi < 4; mi++)
                    acc[mi][ni] = MFMA16(af[mi], bfr, acc[mi][ni]);
            }
        }
    }
#pragma unroll
    for (int mi = 0; mi < 4; mi++)
#pragma unroll
        for (int ni = 0; ni < 4; ni++)
#pragma unroll
            for (int j = 0; j < 4; j++) {
                int r = tile_m + wr * 64 + mi * 16 + (lane >> 4) * 4 + j;
                int c = tile_n + wc * 64 + ni * 16 + (lane & 15);
                float v = acc[mi][ni][j];
                if (MODE == 0) {
                    v = (v + bias[c]) * 0.0625f;
                    ((short*)outp)[(((long)bz * H_ + (c >> 8)) * S_ + r) * DH_ + (c & 255)] = f2bf(v);
                } else if (MODE == 1) {
                    v += bias[c];
                    ((short*)outp)[(((long)bz * H_ + (c >> 8)) * S_ + r) * DH_ + (c & 255)] = f2bf(v);
                } else if (MODE == 2) {
                    v += bias[r];
                    ((short*)outp)[((long)bz * DH_ + r) * S_ + c] = f2bf(v);
                } else {
                    ((float*)outp)[((long)bz * S_ + r) * D_ + c] = v;
                }
            }
}

// ---------------- pass 1: raw logits -> d_out attn region + partial stats ---
// grid (B*H, S/64, 2); 256 thr = 4 waves; wave w owns Q-rows w*16..w*16+15.
// T-chunk of 1024 per z; K tile [8 kk][64 t][32 k] = 32KB, source-swizzled.
__global__ __launch_bounds__(256, 4)
void attn_logits(const short* __restrict__ qsc, const short* __restrict__ ksc,
                 float* __restrict__ attnp, float* __restrict__ rowm_p,
                 float* __restrict__ rowsum_p) {
    __shared__ short Ksh[8 * 64 * 32];  // 32KB
    const int tid = threadIdx.x, wid = tid >> 6, lane = tid & 63;
    const int bh = blockIdx.x;
    const int b = bh >> 2, h = bh & 3;
    const int sg = blockIdx.y * 64;
    const int tz = blockIdx.z;
    const short* qbase = qsc + (((long)b * H_ + h) * S_ + sg) * DH_;
    const short* kbase = ksc + (((long)b * H_ + h) * S_ + tz * 1024) * DH_;
    float* attnbase = attnp + ((long)(b * S_ + sg) * H_ + h) * S_ + tz * 1024;

    // Q fragments straight from global (one-time, 32KB/block)
    bf16x8 qf[8];
    {
        const short* qrow = qbase + (wid * 16 + (lane & 15)) * DH_ + (lane >> 4) * 8;
#pragma unroll
        for (int kk = 0; kk < 8; kk++) qf[kk] = *(const bf16x8*)(qrow + kk * 32);
    }

    float mrun[4], srun[4];
#pragma unroll
    for (int j = 0; j < 4; j++) { mrun[j] = -1e30f; srun[j] = 0.f; }

    for (int tc = 0; tc < 16; tc++) {
        __syncthreads();  // prev MFMA reads done
        // stage K tile: LDS[kk][t][kb], source col pre-swizzled by ((t>>1)&3)<<4
#pragma unroll
        for (int i = 0; i < 8; i++) {
            int off = ((i * 4 + wid) * 64 + lane) * 16;  // 0..32767
            int kk = off >> 12, rem = off & 4095;
            int t = rem >> 6, kb = rem & 63;
            int kbs = kb ^ ((((t >> 1) & 3)) << 4);
            GLD16(kbase + (long)(tc * 64 + t) * DH_ + kk * 32 + (kbs >> 1), ((char*)Ksh) + off);
        }
        __syncthreads();
        f32x4 acc[4];
#pragma unroll
        for (int ni = 0; ni < 4; ni++) acc[ni] = {0.f, 0.f, 0.f, 0.f};
#pragma unroll
        for (int kk = 0; kk < 8; kk++) {
#pragma unroll
            for (int ni = 0; ni < 4; ni++) {
                int t = ni * 16 + (lane & 15);
                int kbyte = ((lane >> 4) * 16) ^ ((((t >> 1) & 3)) << 4);
                bf16x8 bfr = *(const bf16x8*)(((const char*)Ksh) + kk * 4096 + t * 64 + kbyte);
                acc[ni] = MFMA16(qf[kk], bfr, acc[ni]);
            }
        }
        // online stats over this 64-T tile (rows exclusive to this wave)
#pragma unroll
        for (int j = 0; j < 4; j++) {
            float tmax = fmaxf(fmaxf(acc[0][j], acc[1][j]), fmaxf(acc[2][j], acc[3][j]));
#pragma unroll
            for (int m = 1; m < 16; m <<= 1) tmax = fmaxf(tmax, __shfl_xor(tmax, m, 64));
            float mn = fmaxf(mrun[j], tmax);
            float ps = 0.f;
#pragma unroll
            for (int ni = 0; ni < 4; ni++) ps += __expf(acc[ni][j] - mn);
#pragma unroll
            for (int m = 1; m < 16; m <<= 1) ps += __shfl_xor(ps, m, 64);
            srun[j] = srun[j] * __expf(mrun[j] - mn) + ps;
            mrun[j] = mn;
        }
        // raw logits -> d_out attn region ([B,S,H,T])
#pragma unroll
        for (int ni = 0; ni < 4; ni++)
#pragma unroll
            for (int j = 0; j < 4; j++) {
                int r = wid * 16 + (lane >> 4) * 4 + j;
                int t = tc * 64 + ni * 16 + (lane & 15);
                attnbase[(long)r * (H_ * S_) + t] = acc[ni][j];
            }
    }
    // partial stats for this T-half
    if ((lane & 15) == 0) {
#pragma unroll
        for (int j = 0; j < 4; j++) {
            int r = wid * 16 + (lane >> 4) * 4 + j;
            long ridx = (long)tz * BHS_ + ((long)b * H_ + h) * S_ + sg + r;
            rowm_p[ridx] = mrun[j];
            rowsum_p[ridx] = srun[j];
        }
    }
}

// ---------------- pass 2: merge stats + normalize probs in-place + PV partial --
// grid (B*H, S/64, 2); 256 thr = 4 waves; wave w owns e-cols w*64..w*64+63.
__global__ __launch_bounds__(256, 4)
void attn_pv(float* __restrict__ attnp, const short* __restrict__ vsT,
             const float* __restrict__ rowm_p, const float* __restrict__ rowsum_p,
             float* __restrict__ headp) {
    __shared__ short Pl[64 * 64];    // 8KB, XOR-swizzled
    __shared__ short Vsh[256 * 64];  // 32KB, source-swizzled
    const int tid = threadIdx.x, wid = tid >> 6, lane = tid & 63;
    const int bh = blockIdx.x;
    const int b = bh >> 2, h = bh & 3;
    const int sg = blockIdx.y * 64;
    const int tz = blockIdx.z;
    float* attnbase = attnp + ((long)(b * S_ + sg) * H_ + h) * S_ + tz * 1024;
    const short* vbase = vsT + (long)b * DH_ * S_ + tz * 1024;

    // per-thread row stats (4 rows each), merging the two T-half partials
    const int prow0 = tid >> 4, pcol = (tid & 15) * 4;
    float lm[4], li[4];
#pragma unroll
    for (int rr = 0; rr < 4; rr++) {
        long ridx = ((long)b * H_ + h) * S_ + sg + prow0 + rr * 16;
        float m0 = rowm_p[ridx], m1 = rowm_p[BHS_ + ridx];
        float s0 = rowsum_p[ridx], s1 = rowsum_p[BHS_ + ridx];
        float mm = fmaxf(m0, m1);
        float sv = s0 * __expf(m0 - mm) + s1 * __expf(m1 - mm);
        lm[rr] = mm;
        li[rr] = 1.f / sv;
    }

    f32x4 acc[4][4];
#pragma unroll
    for (int i = 0; i < 4; i++)
#pragma unroll
        for (int j = 0; j < 4; j++) acc[i][j] = {0.f, 0.f, 0.f, 0.f};

    // prefetch probs for tc=0
    float4 p[4];
#pragma unroll
    for (int rr = 0; rr < 4; rr++)
        p[rr] = *(const float4*)(attnbase + (long)(prow0 + rr * 16) * (H_ * S_) + pcol);

    for (int tc = 0; tc < 16; tc++) {
        // stage V tile [256 e][64 t] (linear LDS dest, source col pre-swizzled)
#pragma unroll
        for (int i = 0; i < 8; i++) {
            int off = ((i * 4 + wid) * 64 + lane) * 16;  // 0..32767
            int e = off >> 7, cb = off & 127;
            int cbs = cb ^ ((e & 7) << 4);
            GLD16(vbase + (long)e * S_ + tc * 64 + (cbs >> 1), ((char*)Vsh) + off);
        }
        // normalize logits -> probs, write back in place + swizzled bf16 Pl
#pragma unroll
        for (int rr = 0; rr < 4; rr++) {
            int prow = prow0 + rr * 16;
            float4 x = p[rr];
            float4 pr;
            pr.x = __expf(x.x - lm[rr]) * li[rr];
            pr.y = __expf(x.y - lm[rr]) * li[rr];
            pr.z = __expf(x.z - lm[rr]) * li[rr];
            pr.w = __expf(x.w - lm[rr]) * li[rr];
            *(float4*)(attnbase + (long)prow * (H_ * S_) + tc * 64 + pcol) = pr;
            short4 pb;
            pb.x = f2bf(pr.x); pb.y = f2bf(pr.y); pb.z = f2bf(pr.z); pb.w = f2bf(pr.w);
            int wb = (prow * 128 + pcol * 2) ^ ((prow & 7) << 4);
            *(short4*)(((char*)Pl) + wb) = pb;
        }
        __syncthreads();  // V staged + Pl written
        if (tc < 15) {
            // prefetch next tile's logits (latency hides under MFMA + barrier)
#pragma unroll
            for (int rr = 0; rr < 4; rr++)
                p[rr] = *(const float4*)(attnbase + (long)(prow0 + rr * 16) * (H_ * S_) + (tc + 1) * 64 + pcol);
        }
#pragma unroll
        for (int kk = 0; kk < 2; kk++) {
            bf16x8 af[4];
#pragma unroll
            for (int mi = 0; mi < 4; mi++) {
                int s = mi * 16 + (lane & 15);
                int bo = (s * 128 + kk * 64 + (lane >> 4) * 16) ^ ((s & 7) << 4);
                af[mi] = *(const bf16x8*)(((const char*)Pl) + bo);
            }
#pragma unroll
            for (int ni = 0; ni < 4; ni++) {
                int e = wid * 64 + ni * 16 + (lane & 15);
                int bo = (e * 128 + kk * 64 + (lane >> 4) * 16) ^ ((e & 7) << 4);
                bf16x8 bfr = *(const bf16x8*)(((const char*)Vsh) + bo);
#pragma unroll
                for (int mi = 0; mi < 4; mi++)
                    acc[mi][ni] = MFMA16(af[mi], bfr, acc[mi][ni]);
            }
        }
        __syncthreads();  // MFMA reads done before next stage
    }
    // store partial head [z][B,H,S,DH]
#pragma unroll
    for (int mi = 0; mi < 4; mi++)
#pragma unroll
        for (int ni = 0; ni < 4; ni++)
#pragma unroll
            for (int j = 0; j < 4; j++) {
                int r = mi * 16 + (lane >> 4) * 4 + j;
                int c = wid * 64 + ni * 16 + (lane & 15);
                headp[(long)tz * ((long)B_ * H_ * S_ * DH_) +
                      (((long)b * H_ + h) * S_ + sg + r) * DH_ + c] = acc[mi][ni][j];
            }
}

// ---------------- head mean over H and T-partials -> bf16 ----------------
__global__ void head_reduce(const float* __restrict__ headp, short* __restrict__ hmean, int n4) {
    int i = blockIdx.x * blockDim.x + threadIdx.x;
    if (i >= n4) return;
    long f = (long)i * 4;
    int e = (int)(f & (DH_ - 1));
    long bs = f >> 8;
    int b = (int)(bs >> 11), s = (int)(bs & (S_ - 1));
    const long BHSD = (long)B_ * H_ * S_ * DH_;
    float4 sum = {0.f, 0.f, 0.f, 0.f};
#pragma unroll
    for (int z = 0; z < 2; z++)
#pragma unroll
        for (int h = 0; h < H_; h++) {
            float4 a = *(const float4*)&headp[z * BHSD + (((long)b * H_ + h) * S_ + s) * DH_ + e];
            sum.x += a.x; sum.y += a.y; sum.z += a.z; sum.w += a.w;
        }
    short4 o;
    o.x = f2bf(sum.x * 0.25f); o.y = f2bf(sum.y * 0.25f);
    o.z = f2bf(sum.z * 0.25f); o.w = f2bf(sum.w * 0.25f);
    *(short4*)&hmean[f] = o;
}

extern "C" void kernel_launch(void* const* d_in, const int* in_sizes, int n_in,
                              void* d_out, int out_size, void* d_ws, size_t ws_size,
                              hipStream_t stream) {
    (void)in_sizes; (void)n_in; (void)out_size; (void)ws_size;
    const float* q = (const float*)d_in[0];
    const float* k = (const float*)d_in[1];
    const float* v = (const float*)d_in[2];
    const float* vW = (const float*)d_in[3];
    const float* vb = (const float*)d_in[4];
    const float* qW = (const float*)d_in[5];
    const float* qb = (const float*)d_in[6];
    const float* kW = (const float*)d_in[7];
    const float* kb = (const float*)d_in[8];
    const float* wH = (const float*)d_in[9];

    long off = 0;
    char* base = (char*)d_ws;
    auto alloc = [&](long bytes) {
        char* p = base + off;
        off = (off + bytes + 255) & ~255L;
        return p;
    };
    // wh_bf first: must survive until final GEMM (outside headp alias window)
    short* wh_bf = (short*)alloc((long)D_ * DH_ * 2);
    short* q_bf = (short*)alloc((long)B_ * S_ * D_ * 2);   // dead after gemm<0>
    short* k_bf = (short*)alloc((long)B_ * S_ * D_ * 2);   // dead after gemm<1>
    short* v_bf = (short*)alloc((long)B_ * S_ * D_ * 2);   // dead after gemm<2>
    short* wq_bf = (short*)alloc((long)H_ * DH_ * D_ * 2); // dead after gemm<0>
    short* wk_bf = (short*)alloc((long)H_ * DH_ * D_ * 2); // dead after gemm<1>
    short* wv_bf = (short*)alloc((long)DH_ * D_ * 2);      // dead after gemm<2>
    short* qsc = (short*)alloc((long)B_ * H_ * S_ * DH_ * 2);  // dead after pass1
    short* ksc = (short*)alloc((long)B_ * H_ * S_ * DH_ * 2);  // dead after pass1
    short* vsT = (short*)alloc((long)B_ * DH_ * S_ * 2);       // live in pass2
    float* rowm_p = (float*)alloc(2L * BHS_ * 4);
    float* rowsum_p = (float*)alloc(2L * BHS_ * 4);
    // aliases over dead regions:
    //   headp: 2 * 32MB = 64MB starting at q_bf (spans q_bf..qsc[0:11.5MB], all dead in pass2)
    //   hmean: 4MB at ksc (dead after pass1, outside headp's span)
    float* headp = (float*)q_bf;
    short* hmean = ksc;

    float* attnp = (float*)d_out + (long)B_ * S_ * D_;

    auto cvtl = [&](const float* s, short* dst, long n) {
        int n4 = (int)(n / 4);
        cvt_kernel<<<(n4 + 255) / 256, 256, 0, stream>>>(s, dst, n4);
    };
    cvtl(q, q_bf, (long)B_ * S_ * D_);
    cvtl(k, k_bf, (long)B_ * S_ * D_);
    cvtl(v, v_bf, (long)B_ * S_ * D_);
    cvtl(qW, wq_bf, (long)H_ * DH_ * D_);
    cvtl(kW, wk_bf, (long)H_ * DH_ * D_);
    cvtl(vW, wv_bf, (long)DH_ * D_);
    cvtl(wH, wh_bf, (long)D_ * DH_);

    // projections
    gemm_bt<0><<<dim3(D_ / 128, S_ / 128, B_), 256, 0, stream>>>(
        q_bf, (long)S_ * D_, D_, wq_bf, 0L, D_, qb, qsc, D_);
    gemm_bt<1><<<dim3(D_ / 128, S_ / 128, B_), 256, 0, stream>>>(
        k_bf, (long)S_ * D_, D_, wk_bf, 0L, D_, kb, ksc, D_);
    gemm_bt<2><<<dim3(S_ / 128, DH_ / 128, B_), 256, 0, stream>>>(
        wv_bf, 0L, D_, v_bf, (long)S_ * D_, D_, vb, vsT, D_);

    // pass 1: logits + partial stats; pass 2: merge + normalize + PV partials
    attn_logits<<<dim3(B_ * H_, S_ / 64, 2), 256, 0, stream>>>(qsc, ksc, attnp, rowm_p, rowsum_p);
    attn_pv<<<dim3(B_ * H_, S_ / 64, 2), 256, 0, stream>>>(attnp, vsT, rowm_p, rowsum_p, headp);

    // mean over heads/partials + output projection
    int n4 = B_ * S_ * DH_ / 4;
    head_reduce<<<(n4 + 255) / 256, 256, 0, stream>>>(headp, hmean, n4);
    gemm_bt<3><<<dim3(D_ / 128, S_ / 128, B_), 256, 0, stream>>>(
        hmean, (long)S_ * DH_, DH_, wh_bf, 0L, DH_, nullptr, (float*)d_out, DH_);
}